// Round 11
// baseline (144.438 us; speedup 1.0000x reference)
//
#include <hip/hip_runtime.h>
#include <math.h>

typedef __attribute__((ext_vector_type(4))) float f32x4;
typedef __attribute__((ext_vector_type(8))) short s16x8;
typedef __attribute__((ext_vector_type(4))) unsigned int u32x4;
typedef __attribute__((ext_vector_type(2))) unsigned int u32x2;

#define NB 4
#define CH 128
#define ICH 64
#define NSP 4096
#define KSPLIT 8
#define SEGK (NSP / KSPLIT)   // 512
#define LDK 72    // LDS row stride (bf16): 144 B, 16B-aligned, 2-way banks only

static __device__ __forceinline__ unsigned short f2bf(float f) {
  unsigned int u = __builtin_bit_cast(unsigned int, f);
  u += 0x7fffu + ((u >> 16) & 1u);   // RNE
  return (unsigned short)(u >> 16);
}

// ---------------- Kernel 0: all weights fp32 -> bf16, + zero stat ------------
// Wwb layout: [theta 8192][phi 8192][g 8192][W 8192] bf16 elems
__global__ __launch_bounds__(256) void k_wconv(
    const float* __restrict__ tw, const float* __restrict__ pw,
    const float* __restrict__ gw, const float* __restrict__ Ww,
    unsigned short* __restrict__ Wwb, float* __restrict__ stat)
{
  int i = blockIdx.x * 256 + threadIdx.x;   // 8192 threads x 1 float4 chunk
  int which = i >> 11;                      // 2048 chunks per matrix
  const float* src = (which == 0) ? tw : (which == 1) ? pw : (which == 2) ? gw : Ww;
  float4 v = ((const float4*)src)[i & 2047];
  unsigned int p0 = (unsigned int)f2bf(v.x) | ((unsigned int)f2bf(v.y) << 16);
  unsigned int p1 = (unsigned int)f2bf(v.z) | ((unsigned int)f2bf(v.w) << 16);
  *(u32x2*)(Wwb + i * 4) = (u32x2){p0, p1};
  if (blockIdx.x == 0) {                    // stat = 1024 floats = 256 float4
    float4 z = {0.f, 0.f, 0.f, 0.f};
    ((float4*)stat)[threadIdx.x] = z;
  }
}

// ---------------- Kernel 1: ONE projection per block (occupancy fix) ---------
// grid (128, 4, 3): z=0 thetaT [B][N][IC] (log2e-scaled); z=1 phiT; z=2 g [B][IC][N]
// 128 thr (2 waves), 32 n/block; 12 waves/CU (R10 post-mortem: fused-z version
// ran at 1 wave/SIMD -> latency-bound; x re-read 3x (+16 MB) is the cheap price)
__global__ __launch_bounds__(128) void k_proj(
    const float* __restrict__ x,
    const float* __restrict__ gbias, const float* __restrict__ tbias,
    const float* __restrict__ pbias,
    const unsigned short* __restrict__ Wwb,
    unsigned short* __restrict__ thetaT, unsigned short* __restrict__ phiT,
    unsigned short* __restrict__ gout)
{
  __shared__ __align__(16) unsigned short ldsT[32 * LDK];  // staging
  const int b = blockIdx.y, z = blockIdx.z;
  const int n0 = blockIdx.x * 32;
  const int t = threadIdx.x;
  const int wave = t >> 6, lane = t & 63;
  const int l15 = lane & 15, quad = lane >> 4;
  const int n = n0 + wave * 16 + l15;
  const float* xb = x + (size_t)b * CH * NSP;

  s16x8 aq[4];
#pragma unroll
  for (int kc = 0; kc < 4; ++kc)
#pragma unroll
    for (int j = 0; j < 8; ++j)
      aq[kc][j] = (short)f2bf(xb[(size_t)(kc * 32 + quad * 8 + j) * NSP + n]);

  unsigned short* myT = &ldsT[wave * 16 * LDK];
  const int erow = lane >> 3, ecol = (lane & 7) * 8;

  const float* Bz = (z == 0) ? tbias : (z == 1) ? pbias : gbias;
  const float scl = (z == 0) ? 1.44269504f : 1.0f;
  const unsigned short* Wz = Wwb + z * (ICH * CH);
#pragma unroll
  for (int osub = 0; osub < 4; ++osub) {
    f32x4 acc = (f32x4){0.f, 0.f, 0.f, 0.f};
#pragma unroll
    for (int kc = 0; kc < 4; ++kc) {
      s16x8 bw = __builtin_bit_cast(s16x8,
          *(const u32x4*)(Wz + (osub * 16 + l15) * CH + kc * 32 + quad * 8));
      acc = __builtin_amdgcn_mfma_f32_16x16x32_bf16(aq[kc], bw, acc, 0, 0, 0);
    }
    float bv = Bz[osub * 16 + l15];
#pragma unroll
    for (int r = 0; r < 4; ++r)
      myT[(quad * 4 + r) * LDK + osub * 16 + l15] = f2bf((acc[r] + bv) * scl);
  }
  if (z < 2) {
    // wave-private region, in-order LDS: no barrier needed
    unsigned short* outp = ((z == 0) ? thetaT : phiT) + ((size_t)b * NSP + n0 + wave * 16) * ICH;
    u32x4 w0 = *(const u32x4*)(&myT[erow * LDK + ecol]);
    u32x4 w1 = *(const u32x4*)(&myT[(8 + erow) * LDK + ecol]);
    *(u32x4*)(outp + erow * ICH + ecol) = w0;
    *(u32x4*)(outp + (8 + erow) * ICH + ecol) = w1;
  } else {
    // g transpose: 2 insts/thread, each 16 o-rows x 64 B dense (R8 bug fixed)
    __syncthreads();
#pragma unroll
    for (int jj = 0; jj < 2; ++jj) {
      int o = (wave * 2 + jj) * 16 + (lane >> 2);
      int nch = (lane & 3) * 8;
      unsigned short vv[8];
#pragma unroll
      for (int q2 = 0; q2 < 8; ++q2) vv[q2] = ldsT[(nch + q2) * LDK + o];
      unsigned int words[4];
#pragma unroll
      for (int i2 = 0; i2 < 4; ++i2)
        words[i2] = (unsigned int)vv[2 * i2] | ((unsigned int)vv[2 * i2 + 1] << 16);
      *(u32x4*)(gout + ((size_t)b * ICH + o) * NSP + n0 + nch) =
          (u32x4){words[0], words[1], words[2], words[3]};
    }
  }
}

// ---------------- Kernel 2: flash attention partials (FROZEN, R10) -----------
__global__ __launch_bounds__(256, 2) void k_attn(
    const unsigned short* __restrict__ thetaT,
    const unsigned short* __restrict__ phiT,
    const unsigned short* __restrict__ gmat,
    unsigned short* __restrict__ Opart, float* __restrict__ lpart)
{
  __shared__ unsigned short ldsK[2][64 * LDK];
  __shared__ unsigned short ldsV[2][64 * LDK];
  __shared__ unsigned short ldsP[4][16 * LDK];   // per-wave P / O-staging
  const int qt = blockIdx.x, b = blockIdx.y, seg = blockIdx.z;
  const int t = threadIdx.x;
  const int wave = t >> 6, lane = t & 63;
  const int l15 = lane & 15, quad = lane >> 4;
  const int q0 = qt * 256 + wave * 64;

  s16x8 aq[4][2];
  const unsigned short* th = thetaT + ((size_t)b * NSP + q0) * ICH;
#pragma unroll
  for (int qs = 0; qs < 4; ++qs)
#pragma unroll
    for (int ks = 0; ks < 2; ++ks)
      aq[qs][ks] = __builtin_bit_cast(s16x8,
          *(const u32x4*)(th + (qs * 16 + l15) * ICH + ks * 32 + quad * 8));

  f32x4 Oacc[4][4];
  f32x4 lacc[4];
#pragma unroll
  for (int i = 0; i < 4; ++i) {
    lacc[i] = (f32x4){0.f, 0.f, 0.f, 0.f};
#pragma unroll
    for (int j = 0; j < 4; ++j) Oacc[i][j] = (f32x4){0.f, 0.f, 0.f, 0.f};
  }

  s16x8 bones;
  {
    short v = (l15 == 0) ? (short)0x3F80 : (short)0;
#pragma unroll
    for (int j = 0; j < 8; ++j) bones[j] = v;
  }

  const unsigned short* ph = phiT + (size_t)b * NSP * ICH;
  const unsigned short* gb = gmat + (size_t)b * ICH * NSP;
  const int k0 = seg * SEGK;

  auto load_tile = [&](int key0, u32x4* pf) {
#pragma unroll
    for (int i = 0; i < 4; ++i) {
      int idx = t + 256 * i;
      int r2 = (idx >> 3) & 63, c8 = (idx & 7) * 8;
      pf[i] = (idx < 512)
          ? *(const u32x4*)(ph + (size_t)(key0 + r2) * ICH + c8)
          : *(const u32x4*)(gb + (size_t)r2 * NSP + key0 + c8);
    }
  };
  auto store_tile = [&](int buf, const u32x4* pf) {
#pragma unroll
    for (int i = 0; i < 4; ++i) {
      int idx = t + 256 * i;
      int r2 = (idx >> 3) & 63, c8 = (idx & 7) * 8;
      if (idx < 512) *(u32x4*)(&ldsK[buf][r2 * LDK + c8]) = pf[i];
      else           *(u32x4*)(&ldsV[buf][r2 * LDK + c8]) = pf[i];
    }
  };

  u32x4 pf[4];
  load_tile(k0, pf);
  store_tile(0, pf);
  __syncthreads();

  for (int kt = 0; kt < SEGK / 64; ++kt) {
    const int cur = kt & 1;
    const bool more = (kt + 1) < SEGK / 64;
    if (more) load_tile(k0 + (kt + 1) * 64, pf);

    s16x8 bk[4][2];
#pragma unroll
    for (int kc = 0; kc < 4; ++kc)
#pragma unroll
      for (int ks = 0; ks < 2; ++ks)
        bk[kc][ks] = *(const s16x8*)(&ldsK[cur][(kc * 16 + l15) * LDK + ks * 32 + quad * 8]);
    s16x8 bv[2][4];
#pragma unroll
    for (int ks = 0; ks < 2; ++ks)
#pragma unroll
      for (int ds = 0; ds < 4; ++ds)
        bv[ks][ds] = *(const s16x8*)(&ldsV[cur][(ds * 16 + l15) * LDK + ks * 32 + quad * 8]);

    unsigned short* myP = &ldsP[wave][0];
#pragma unroll
    for (int qs = 0; qs < 4; ++qs) {
#pragma unroll
      for (int kc = 0; kc < 4; ++kc) {
        f32x4 sacc = (f32x4){0.f, 0.f, 0.f, 0.f};
        sacc = __builtin_amdgcn_mfma_f32_16x16x32_bf16(aq[qs][0], bk[kc][0], sacc, 0, 0, 0);
        sacc = __builtin_amdgcn_mfma_f32_16x16x32_bf16(aq[qs][1], bk[kc][1], sacc, 0, 0, 0);
#pragma unroll
        for (int r = 0; r < 4; ++r) {
          float e = exp2f(sacc[r]);        // theta carries log2(e)
          myP[(quad * 4 + r) * LDK + kc * 16 + l15] =
              (unsigned short)(__builtin_bit_cast(unsigned int, e) >> 16);  // trunc bf16
        }
      }
#pragma unroll
      for (int ks = 0; ks < 2; ++ks) {
        s16x8 ap = *(const s16x8*)(&myP[l15 * LDK + ks * 32 + quad * 8]);
        lacc[qs] = __builtin_amdgcn_mfma_f32_16x16x32_bf16(ap, bones, lacc[qs], 0, 0, 0);
#pragma unroll
        for (int ds = 0; ds < 4; ++ds)
          Oacc[qs][ds] = __builtin_amdgcn_mfma_f32_16x16x32_bf16(ap, bv[ks][ds], Oacc[qs][ds], 0, 0, 0);
      }
    }

    if (more) {
      store_tile(cur ^ 1, pf);
      __syncthreads();           // ONE barrier per kt
    }
  }

  unsigned short* Ob = Opart + (((size_t)seg * NB + b) * NSP + q0) * ICH;
  unsigned short* myP = &ldsP[wave][0];
  const int erow = lane >> 3;
  const int ecol = (lane & 7) * 8;
#pragma unroll
  for (int qs = 0; qs < 4; ++qs) {
#pragma unroll
    for (int ds = 0; ds < 4; ++ds)
#pragma unroll
      for (int r = 0; r < 4; ++r)
        myP[(quad * 4 + r) * LDK + ds * 16 + l15] = f2bf(Oacc[qs][ds][r]);
    u32x4 w0 = *(const u32x4*)(&myP[erow * LDK + ecol]);
    u32x4 w1 = *(const u32x4*)(&myP[(8 + erow) * LDK + ecol]);
    *(u32x4*)(Ob + (qs * 16 + erow) * ICH + ecol) = w0;
    *(u32x4*)(Ob + (qs * 16 + 8 + erow) * ICH + ecol) = w1;
  }
  {
    float* myPf = (float*)myP;
    if (l15 == 0) {
#pragma unroll
      for (int qs = 0; qs < 4; ++qs)
#pragma unroll
        for (int r = 0; r < 4; ++r)
          myPf[qs * 16 + quad * 4 + r] = lacc[qs][r];
    }
    float* lb = lpart + ((size_t)seg * NB + b) * NSP + q0;
    lb[lane] = myPf[lane];
  }
}

// ---------------- Kernel 3a: combine partials + W-proj + stats ---------------
// Occupancy fix: grid (256,4) x 128 thr; wave w covers 16 n x 64 co (co-split)
// -> 2048 waves = 8 waves/CU (was 4). Opart read duplicated (+16 MB) -- cheap
// vs 2x latency hiding at 1 wave/SIMD.
__global__ __launch_bounds__(128) void k_wy(
    const unsigned short* __restrict__ Opart, const float* __restrict__ lpart,
    const unsigned short* __restrict__ Wwb,
    float* __restrict__ WyT, float* __restrict__ stat)
{
  const int b = blockIdx.y, nt = blockIdx.x;   // nt 0..255 -> 16 n per block
  const int t = threadIdx.x;
  const int wave = t >> 6, lane = t & 63;
  const int l15 = lane & 15, quad = lane >> 4;
  const int n0 = nt * 16;
  const int cb = wave * 64;                    // co half per wave
  float ls = 0.f;
#pragma unroll
  for (int s = 0; s < KSPLIT; ++s)
    ls += lpart[((size_t)s * NB + b) * NSP + n0 + l15];
  float inv = 1.0f / ls;
  s16x8 ay[2];
#pragma unroll
  for (int ks = 0; ks < 2; ++ks) {
    float acc8[8];
#pragma unroll
    for (int j = 0; j < 8; ++j) acc8[j] = 0.f;
#pragma unroll
    for (int s = 0; s < KSPLIT; ++s) {
      const unsigned short* op =
          Opart + (((size_t)s * NB + b) * NSP + n0 + l15) * ICH + ks * 32 + quad * 8;
      u32x4 raw = *(const u32x4*)op;
#pragma unroll
      for (int w2 = 0; w2 < 4; ++w2) {
        unsigned int u = raw[w2];
        acc8[2 * w2]     += __builtin_bit_cast(float, u << 16);
        acc8[2 * w2 + 1] += __builtin_bit_cast(float, u & 0xFFFF0000u);
      }
    }
#pragma unroll
    for (int j = 0; j < 8; ++j) ay[ks][j] = (short)f2bf(acc8[j] * inv);
  }
  const unsigned short* Wb = Wwb + 3 * (ICH * CH);   // W region
  s16x8 bw[4][2];
#pragma unroll
  for (int cc = 0; cc < 4; ++cc)
#pragma unroll
    for (int ks = 0; ks < 2; ++ks)
      bw[cc][ks] = __builtin_bit_cast(s16x8,
          *(const u32x4*)(Wb + (cb + cc * 16 + l15) * ICH + ks * 32 + quad * 8));
  float sums[4], sq[4];
#pragma unroll
  for (int cc = 0; cc < 4; ++cc) { sums[cc] = 0.f; sq[cc] = 0.f; }
#pragma unroll
  for (int cc = 0; cc < 4; ++cc) {
    f32x4 acc = (f32x4){0.f, 0.f, 0.f, 0.f};
    acc = __builtin_amdgcn_mfma_f32_16x16x32_bf16(ay[0], bw[cc][0], acc, 0, 0, 0);
    acc = __builtin_amdgcn_mfma_f32_16x16x32_bf16(ay[1], bw[cc][1], acc, 0, 0, 0);
    float* wout = WyT + ((size_t)b * NSP + n0 + quad * 4) * CH + cb + cc * 16 + l15;
#pragma unroll
    for (int r = 0; r < 4; ++r) {
      float v = acc[r];
      sums[cc] += v;
      sq[cc] += v * v;
      wout[r * CH] = v;
    }
  }
#pragma unroll
  for (int cc = 0; cc < 4; ++cc) {
    sums[cc] += __shfl_xor(sums[cc], 16, 64);
    sums[cc] += __shfl_xor(sums[cc], 32, 64);
    sq[cc] += __shfl_xor(sq[cc], 16, 64);
    sq[cc] += __shfl_xor(sq[cc], 32, 64);
  }
  if (quad == 0) {
#pragma unroll
    for (int cc = 0; cc < 4; ++cc) {
      atomicAdd(&stat[(b * CH + cb + cc * 16 + l15) * 2 + 0], sums[cc]);
      atomicAdd(&stat[(b * CH + cb + cc * 16 + l15) * 2 + 1], sq[cc]);
    }
  }
}

// ---------------- Kernel 3b: InstanceNorm + residual, out [B][C][N] ---------
__global__ __launch_bounds__(256) void k_norm(
    const float* __restrict__ WyT, const float* __restrict__ stat,
    const float* __restrict__ x, float* __restrict__ out)
{
  __shared__ float sWy[32 * 132];
  const int nt = blockIdx.x;        // 0..127
  const int b = blockIdx.y;
  const int t = threadIdx.x;
  const int n0 = nt * 32;
#pragma unroll
  for (int i = 0; i < 4; ++i) {
    int idx = t + 256 * i;
    int row = idx >> 5, c4 = idx & 31;
    *(float4*)(&sWy[row * 132 + c4 * 4]) =
        *(const float4*)(WyT + ((size_t)b * NSP + n0 + row) * CH + c4 * 4);
  }
  __syncthreads();
#pragma unroll
  for (int j = 0; j < 4; ++j) {
    int u = t + 256 * j;
    int co = u >> 3, nq = u & 7;
    float s = stat[(b * CH + co) * 2 + 0];
    float ss = stat[(b * CH + co) * 2 + 1];
    float mean = s * (1.f / NSP);
    float var = ss * (1.f / NSP) - mean * mean;
    float rs = rsqrtf(var + 1e-5f);
    float4 xv = *(const float4*)(x + (size_t)(b * CH + co) * NSP + n0 + nq * 4);
    float4 ov;
    ov.x = xv.x + (sWy[(nq * 4 + 0) * 132 + co] - mean) * rs;
    ov.y = xv.y + (sWy[(nq * 4 + 1) * 132 + co] - mean) * rs;
    ov.z = xv.z + (sWy[(nq * 4 + 2) * 132 + co] - mean) * rs;
    ov.w = xv.w + (sWy[(nq * 4 + 3) * 132 + co] - mean) * rs;
    *(float4*)(out + (size_t)(b * CH + co) * NSP + n0 + nq * 4) = ov;
  }
}

extern "C" void kernel_launch(void* const* d_in, const int* in_sizes, int n_in,
                              void* d_out, int out_size, void* d_ws, size_t ws_size,
                              hipStream_t stream)
{
  const float* x  = (const float*)d_in[0];
  const float* gw = (const float*)d_in[1];
  const float* gb = (const float*)d_in[2];
  const float* tw = (const float*)d_in[3];
  const float* tb = (const float*)d_in[4];
  const float* pw = (const float*)d_in[5];
  const float* pb = (const float*)d_in[6];
  const float* Ww = (const float*)d_in[7];
  // d_in[8] = W_b: canceled by InstanceNorm -> unused
  float* out = (float*)d_out;
  char* ws = (char*)d_ws;
  // workspace layout (~33 MB)
  unsigned short* thetaT = (unsigned short*)(ws);                        // 2 MB
  unsigned short* phiT   = (unsigned short*)(ws + (2ull << 20));         // 2 MB
  unsigned short* gmat   = (unsigned short*)(ws + (4ull << 20));         // 2 MB
  float* WyT   = (float*)(ws + (8ull << 20));                            // 8 MB
  float* stat  = (float*)(ws + (16ull << 20));                           // 4 KB
  unsigned short* Wwb = (unsigned short*)(ws + (16ull << 20) + 65536);   // 64 KB
  float* lpart = (float*)(ws + (16ull << 20) + (1ull << 19));            // 512 KB
  unsigned short* Opart = (unsigned short*)(ws + (17ull << 20));         // 16 MB

  k_wconv<<<dim3(32), 256, 0, stream>>>(tw, pw, gw, Ww, Wwb, stat);
  k_proj<<<dim3(128, 4, 3), 128, 0, stream>>>(x, gb, tb, pb, Wwb, thetaT, phiT, gmat);
  k_attn<<<dim3(16, 4, KSPLIT), 256, 0, stream>>>(thetaT, phiT, gmat, Opart, lpart);
  k_wy<<<dim3(256, 4), 128, 0, stream>>>(Opart, lpart, Wwb, WyT, stat);
  k_norm<<<dim3(128, 4), 256, 0, stream>>>(WyT, stat, x, out);
}

// Round 12
// 139.216 us; speedup vs baseline: 1.0375x; 1.0375x over previous
//
#include <hip/hip_runtime.h>
#include <math.h>

typedef __attribute__((ext_vector_type(4))) float f32x4;
typedef __attribute__((ext_vector_type(8))) short s16x8;
typedef __attribute__((ext_vector_type(4))) unsigned int u32x4;
typedef __attribute__((ext_vector_type(2))) unsigned int u32x2;

#define NB 4
#define CH 128
#define ICH 64
#define NSP 4096
#define KSPLIT 8
#define SEGK (NSP / KSPLIT)   // 512
#define LDK 72    // LDS row stride (bf16): 144 B, 16B-aligned, 2-way banks only

static __device__ __forceinline__ unsigned short f2bf(float f) {
  unsigned int u = __builtin_bit_cast(unsigned int, f);
  u += 0x7fffu + ((u >> 16) & 1u);   // RNE
  return (unsigned short)(u >> 16);
}

// ---------------- Kernel 0: all weights fp32 -> bf16, + zero stat ------------
// Wwb layout: [theta 8192][phi 8192][g 8192][W 8192] bf16 elems
__global__ __launch_bounds__(256) void k_wconv(
    const float* __restrict__ tw, const float* __restrict__ pw,
    const float* __restrict__ gw, const float* __restrict__ Ww,
    unsigned short* __restrict__ Wwb, float* __restrict__ stat)
{
  int i = blockIdx.x * 256 + threadIdx.x;   // 8192 threads x 1 float4 chunk
  int which = i >> 11;                      // 2048 chunks per matrix
  const float* src = (which == 0) ? tw : (which == 1) ? pw : (which == 2) ? gw : Ww;
  float4 v = ((const float4*)src)[i & 2047];
  unsigned int p0 = (unsigned int)f2bf(v.x) | ((unsigned int)f2bf(v.y) << 16);
  unsigned int p1 = (unsigned int)f2bf(v.z) | ((unsigned int)f2bf(v.w) << 16);
  *(u32x2*)(Wwb + i * 4) = (u32x2){p0, p1};
  if (blockIdx.x == 0) {                    // stat = 1024 floats = 256 float4
    float4 z = {0.f, 0.f, 0.f, 0.f};
    ((float4*)stat)[threadIdx.x] = z;
  }
}

// ---------------- Kernel 1: all 3 projections per block (MFMA) ---------------
// thetaT [B][N][IC] (pre-scaled by log2e); phiT [B][N][IC]; g [B][IC][N]
// R12 note: per-z blocks (R11) regressed — x re-read 3x cost more than the
// occupancy gain; this kernel is within ~2x of its traffic floor as-is.
__global__ __launch_bounds__(128) void k_proj(
    const float* __restrict__ x,
    const float* __restrict__ gbias, const float* __restrict__ tbias,
    const float* __restrict__ pbias,
    const unsigned short* __restrict__ Wwb,
    unsigned short* __restrict__ thetaT, unsigned short* __restrict__ phiT,
    unsigned short* __restrict__ gout)
{
  __shared__ __align__(16) unsigned short ldsT[32 * LDK];  // C-tile staging
  const int b = blockIdx.y;
  const int n0 = blockIdx.x * 32;
  const int t = threadIdx.x;
  const int wave = t >> 6, lane = t & 63;
  const int l15 = lane & 15, quad = lane >> 4;
  const int n = n0 + wave * 16 + l15;
  const float* xb = x + (size_t)b * CH * NSP;

  s16x8 aq[4];
#pragma unroll
  for (int kc = 0; kc < 4; ++kc)
#pragma unroll
    for (int j = 0; j < 8; ++j)
      aq[kc][j] = (short)f2bf(xb[(size_t)(kc * 32 + quad * 8 + j) * NSP + n]);

  unsigned short* myT = &ldsT[wave * 16 * LDK];
  const int erow = lane >> 3, ecol = (lane & 7) * 8;

#pragma unroll
  for (int z = 0; z < 3; ++z) {
    const float* Bz = (z == 0) ? tbias : (z == 1) ? pbias : gbias;
    const float scl = (z == 0) ? 1.44269504f : 1.0f;
    const unsigned short* Wz = Wwb + z * (ICH * CH);
#pragma unroll
    for (int osub = 0; osub < 4; ++osub) {
      f32x4 acc = (f32x4){0.f, 0.f, 0.f, 0.f};
#pragma unroll
      for (int kc = 0; kc < 4; ++kc) {
        s16x8 bw = __builtin_bit_cast(s16x8,
            *(const u32x4*)(Wz + (osub * 16 + l15) * CH + kc * 32 + quad * 8));
        acc = __builtin_amdgcn_mfma_f32_16x16x32_bf16(aq[kc], bw, acc, 0, 0, 0);
      }
      float bv = Bz[osub * 16 + l15];
#pragma unroll
      for (int r = 0; r < 4; ++r)
        myT[(quad * 4 + r) * LDK + osub * 16 + l15] = f2bf((acc[r] + bv) * scl);
    }
    if (z < 2) {
      unsigned short* outp = ((z == 0) ? thetaT : phiT) + ((size_t)b * NSP + n0 + wave * 16) * ICH;
      u32x4 w0 = *(const u32x4*)(&myT[erow * LDK + ecol]);
      u32x4 w1 = *(const u32x4*)(&myT[(8 + erow) * LDK + ecol]);
      *(u32x4*)(outp + erow * ICH + ecol) = w0;
      *(u32x4*)(outp + (8 + erow) * ICH + ecol) = w1;
    } else {
      // g transpose: 2 insts/thread, each 16 o-rows x 64 B dense (R8 bug fixed)
      __syncthreads();
#pragma unroll
      for (int jj = 0; jj < 2; ++jj) {
        int o = (wave * 2 + jj) * 16 + (lane >> 2);
        int nch = (lane & 3) * 8;
        unsigned short vv[8];
#pragma unroll
        for (int q2 = 0; q2 < 8; ++q2) vv[q2] = ldsT[(nch + q2) * LDK + o];
        unsigned int words[4];
#pragma unroll
        for (int i2 = 0; i2 < 4; ++i2)
          words[i2] = (unsigned int)vv[2 * i2] | ((unsigned int)vv[2 * i2 + 1] << 16);
        *(u32x4*)(gout + ((size_t)b * ICH + o) * NSP + n0 + nch) =
            (u32x4){words[0], words[1], words[2], words[3]};
      }
    }
  }
}

// ---------------- Kernel 2: flash attention partials (FROZEN, R10) -----------
// 4 waves, 64 q/wave, K-tile 64, KSPLIT 8, (256,2) no-spill, double-buffered
// staging with register prefetch + ONE barrier/kt. Structural ledger: dbuf +2us;
// all occupancy/tile variants negative (R3-R7); ~40us local optimum.
__global__ __launch_bounds__(256, 2) void k_attn(
    const unsigned short* __restrict__ thetaT,
    const unsigned short* __restrict__ phiT,
    const unsigned short* __restrict__ gmat,
    unsigned short* __restrict__ Opart, float* __restrict__ lpart)
{
  __shared__ unsigned short ldsK[2][64 * LDK];
  __shared__ unsigned short ldsV[2][64 * LDK];
  __shared__ unsigned short ldsP[4][16 * LDK];   // per-wave P / O-staging
  const int qt = blockIdx.x, b = blockIdx.y, seg = blockIdx.z;
  const int t = threadIdx.x;
  const int wave = t >> 6, lane = t & 63;
  const int l15 = lane & 15, quad = lane >> 4;
  const int q0 = qt * 256 + wave * 64;

  s16x8 aq[4][2];
  const unsigned short* th = thetaT + ((size_t)b * NSP + q0) * ICH;
#pragma unroll
  for (int qs = 0; qs < 4; ++qs)
#pragma unroll
    for (int ks = 0; ks < 2; ++ks)
      aq[qs][ks] = __builtin_bit_cast(s16x8,
          *(const u32x4*)(th + (qs * 16 + l15) * ICH + ks * 32 + quad * 8));

  f32x4 Oacc[4][4];
  f32x4 lacc[4];
#pragma unroll
  for (int i = 0; i < 4; ++i) {
    lacc[i] = (f32x4){0.f, 0.f, 0.f, 0.f};
#pragma unroll
    for (int j = 0; j < 4; ++j) Oacc[i][j] = (f32x4){0.f, 0.f, 0.f, 0.f};
  }

  // ones-column B-frag: B[k][n]=(n==0) -> C col 0 = row-sum of A
  s16x8 bones;
  {
    short v = (l15 == 0) ? (short)0x3F80 : (short)0;
#pragma unroll
    for (int j = 0; j < 8; ++j) bones[j] = v;
  }

  const unsigned short* ph = phiT + (size_t)b * NSP * ICH;
  const unsigned short* gb = gmat + (size_t)b * ICH * NSP;
  const int k0 = seg * SEGK;

  auto load_tile = [&](int key0, u32x4* pf) {
#pragma unroll
    for (int i = 0; i < 4; ++i) {
      int idx = t + 256 * i;
      int r2 = (idx >> 3) & 63, c8 = (idx & 7) * 8;
      pf[i] = (idx < 512)
          ? *(const u32x4*)(ph + (size_t)(key0 + r2) * ICH + c8)
          : *(const u32x4*)(gb + (size_t)r2 * NSP + key0 + c8);
    }
  };
  auto store_tile = [&](int buf, const u32x4* pf) {
#pragma unroll
    for (int i = 0; i < 4; ++i) {
      int idx = t + 256 * i;
      int r2 = (idx >> 3) & 63, c8 = (idx & 7) * 8;
      if (idx < 512) *(u32x4*)(&ldsK[buf][r2 * LDK + c8]) = pf[i];
      else           *(u32x4*)(&ldsV[buf][r2 * LDK + c8]) = pf[i];
    }
  };

  u32x4 pf[4];
  load_tile(k0, pf);
  store_tile(0, pf);
  __syncthreads();

  for (int kt = 0; kt < SEGK / 64; ++kt) {
    const int cur = kt & 1;
    const bool more = (kt + 1) < SEGK / 64;
    if (more) load_tile(k0 + (kt + 1) * 64, pf);   // latency overlaps compute

    s16x8 bk[4][2];
#pragma unroll
    for (int kc = 0; kc < 4; ++kc)
#pragma unroll
      for (int ks = 0; ks < 2; ++ks)
        bk[kc][ks] = *(const s16x8*)(&ldsK[cur][(kc * 16 + l15) * LDK + ks * 32 + quad * 8]);
    s16x8 bv[2][4];
#pragma unroll
    for (int ks = 0; ks < 2; ++ks)
#pragma unroll
      for (int ds = 0; ds < 4; ++ds)
        bv[ks][ds] = *(const s16x8*)(&ldsV[cur][(ds * 16 + l15) * LDK + ks * 32 + quad * 8]);

    unsigned short* myP = &ldsP[wave][0];
#pragma unroll
    for (int qs = 0; qs < 4; ++qs) {
#pragma unroll
      for (int kc = 0; kc < 4; ++kc) {
        f32x4 sacc = (f32x4){0.f, 0.f, 0.f, 0.f};
        sacc = __builtin_amdgcn_mfma_f32_16x16x32_bf16(aq[qs][0], bk[kc][0], sacc, 0, 0, 0);
        sacc = __builtin_amdgcn_mfma_f32_16x16x32_bf16(aq[qs][1], bk[kc][1], sacc, 0, 0, 0);
#pragma unroll
        for (int r = 0; r < 4; ++r) {
          float e = exp2f(sacc[r]);        // theta carries log2(e)
          myP[(quad * 4 + r) * LDK + kc * 16 + l15] =
              (unsigned short)(__builtin_bit_cast(unsigned int, e) >> 16);  // trunc bf16
        }
      }
      // consume P immediately (wave-private LDS, in-order)
#pragma unroll
      for (int ks = 0; ks < 2; ++ks) {
        s16x8 ap = *(const s16x8*)(&myP[l15 * LDK + ks * 32 + quad * 8]);
        lacc[qs] = __builtin_amdgcn_mfma_f32_16x16x32_bf16(ap, bones, lacc[qs], 0, 0, 0);
#pragma unroll
        for (int ds = 0; ds < 4; ++ds)
          Oacc[qs][ds] = __builtin_amdgcn_mfma_f32_16x16x32_bf16(ap, bv[ks][ds], Oacc[qs][ds], 0, 0, 0);
      }
    }

    if (more) {
      store_tile(cur ^ 1, pf);   // other buffer: kt-1 readers passed last barrier
      __syncthreads();           // ONE barrier per kt
    }
  }

  // epilogue: O -> wave-private LDS (C-layout) -> 1-KB-dense bf16 stores
  unsigned short* Ob = Opart + (((size_t)seg * NB + b) * NSP + q0) * ICH;
  unsigned short* myP = &ldsP[wave][0];
  const int erow = lane >> 3;
  const int ecol = (lane & 7) * 8;
#pragma unroll
  for (int qs = 0; qs < 4; ++qs) {
#pragma unroll
    for (int ds = 0; ds < 4; ++ds)
#pragma unroll
      for (int r = 0; r < 4; ++r)
        myP[(quad * 4 + r) * LDK + ds * 16 + l15] = f2bf(Oacc[qs][ds][r]);
    u32x4 w0 = *(const u32x4*)(&myP[erow * LDK + ecol]);
    u32x4 w1 = *(const u32x4*)(&myP[(8 + erow) * LDK + ecol]);
    *(u32x4*)(Ob + (qs * 16 + erow) * ICH + ecol) = w0;
    *(u32x4*)(Ob + (qs * 16 + 8 + erow) * ICH + ecol) = w1;
  }
  // l: stage to LDS, one 256-B dense store per wave
  {
    float* myPf = (float*)myP;
    if (l15 == 0) {
#pragma unroll
      for (int qs = 0; qs < 4; ++qs)
#pragma unroll
        for (int r = 0; r < 4; ++r)
          myPf[qs * 16 + quad * 4 + r] = lacc[qs][r];
    }
    float* lb = lpart + ((size_t)seg * NB + b) * NSP + q0;
    lb[lane] = myPf[lane];
  }
}

// ---------------- Kernel 3a: combine partials + W-proj + stats ---------------
// R12 note: co-split occupancy variant (R11) regressed — Opart re-read cost
// exceeded the latency-hiding gain; kernel is near its traffic floor as-is.
__global__ __launch_bounds__(128) void k_wy(
    const unsigned short* __restrict__ Opart, const float* __restrict__ lpart,
    const unsigned short* __restrict__ Wwb,
    float* __restrict__ WyT, float* __restrict__ stat)
{
  const int b = blockIdx.y, nt = blockIdx.x;   // nt 0..127
  const int t = threadIdx.x;
  const int wave = t >> 6, lane = t & 63;
  const int l15 = lane & 15, quad = lane >> 4;
  const int n0 = nt * 32 + wave * 16;
  float ls = 0.f;
#pragma unroll
  for (int s = 0; s < KSPLIT; ++s)
    ls += lpart[((size_t)s * NB + b) * NSP + n0 + l15];
  float inv = 1.0f / ls;
  s16x8 ay[2];
#pragma unroll
  for (int ks = 0; ks < 2; ++ks) {
    float acc8[8];
#pragma unroll
    for (int j = 0; j < 8; ++j) acc8[j] = 0.f;
#pragma unroll
    for (int s = 0; s < KSPLIT; ++s) {
      const unsigned short* op =
          Opart + (((size_t)s * NB + b) * NSP + n0 + l15) * ICH + ks * 32 + quad * 8;
      u32x4 raw = *(const u32x4*)op;
#pragma unroll
      for (int w2 = 0; w2 < 4; ++w2) {
        unsigned int u = raw[w2];
        acc8[2 * w2]     += __builtin_bit_cast(float, u << 16);
        acc8[2 * w2 + 1] += __builtin_bit_cast(float, u & 0xFFFF0000u);
      }
    }
#pragma unroll
    for (int j = 0; j < 8; ++j) ay[ks][j] = (short)f2bf(acc8[j] * inv);
  }
  const unsigned short* Wb = Wwb + 3 * (ICH * CH);   // W region
  s16x8 bw[8][2];
#pragma unroll
  for (int cc = 0; cc < 8; ++cc)
#pragma unroll
    for (int ks = 0; ks < 2; ++ks)
      bw[cc][ks] = __builtin_bit_cast(s16x8,
          *(const u32x4*)(Wb + (cc * 16 + l15) * ICH + ks * 32 + quad * 8));
  float sums[8], sq[8];
#pragma unroll
  for (int cc = 0; cc < 8; ++cc) { sums[cc] = 0.f; sq[cc] = 0.f; }
#pragma unroll
  for (int cc = 0; cc < 8; ++cc) {
    f32x4 acc = (f32x4){0.f, 0.f, 0.f, 0.f};
    acc = __builtin_amdgcn_mfma_f32_16x16x32_bf16(ay[0], bw[cc][0], acc, 0, 0, 0);
    acc = __builtin_amdgcn_mfma_f32_16x16x32_bf16(ay[1], bw[cc][1], acc, 0, 0, 0);
    float* wout = WyT + ((size_t)b * NSP + n0 + quad * 4) * CH + cc * 16 + l15;
#pragma unroll
    for (int r = 0; r < 4; ++r) {
      float v = acc[r];
      sums[cc] += v;
      sq[cc] += v * v;
      wout[r * CH] = v;   // 16 lanes x 4 B = full 64-B sector per quad row
    }
  }
#pragma unroll
  for (int cc = 0; cc < 8; ++cc) {
    sums[cc] += __shfl_xor(sums[cc], 16, 64);
    sums[cc] += __shfl_xor(sums[cc], 32, 64);
    sq[cc] += __shfl_xor(sq[cc], 16, 64);
    sq[cc] += __shfl_xor(sq[cc], 32, 64);
  }
  if (quad == 0) {
#pragma unroll
    for (int cc = 0; cc < 8; ++cc) {
      atomicAdd(&stat[(b * CH + cc * 16 + l15) * 2 + 0], sums[cc]);
      atomicAdd(&stat[(b * CH + cc * 16 + l15) * 2 + 1], sq[cc]);
    }
  }
}

// ---------------- Kernel 3b: InstanceNorm + residual, out [B][C][N] ---------
__global__ __launch_bounds__(256) void k_norm(
    const float* __restrict__ WyT, const float* __restrict__ stat,
    const float* __restrict__ x, float* __restrict__ out)
{
  __shared__ float sWy[32 * 132];
  const int nt = blockIdx.x;        // 0..127
  const int b = blockIdx.y;
  const int t = threadIdx.x;
  const int n0 = nt * 32;
#pragma unroll
  for (int i = 0; i < 4; ++i) {
    int idx = t + 256 * i;
    int row = idx >> 5, c4 = idx & 31;
    *(float4*)(&sWy[row * 132 + c4 * 4]) =
        *(const float4*)(WyT + ((size_t)b * NSP + n0 + row) * CH + c4 * 4);
  }
  __syncthreads();
#pragma unroll
  for (int j = 0; j < 4; ++j) {
    int u = t + 256 * j;
    int co = u >> 3, nq = u & 7;
    float s = stat[(b * CH + co) * 2 + 0];
    float ss = stat[(b * CH + co) * 2 + 1];
    float mean = s * (1.f / NSP);
    float var = ss * (1.f / NSP) - mean * mean;
    float rs = rsqrtf(var + 1e-5f);
    float4 xv = *(const float4*)(x + (size_t)(b * CH + co) * NSP + n0 + nq * 4);
    float4 ov;
    ov.x = xv.x + (sWy[(nq * 4 + 0) * 132 + co] - mean) * rs;
    ov.y = xv.y + (sWy[(nq * 4 + 1) * 132 + co] - mean) * rs;
    ov.z = xv.z + (sWy[(nq * 4 + 2) * 132 + co] - mean) * rs;
    ov.w = xv.w + (sWy[(nq * 4 + 3) * 132 + co] - mean) * rs;
    *(float4*)(out + (size_t)(b * CH + co) * NSP + n0 + nq * 4) = ov;
  }
}

extern "C" void kernel_launch(void* const* d_in, const int* in_sizes, int n_in,
                              void* d_out, int out_size, void* d_ws, size_t ws_size,
                              hipStream_t stream)
{
  const float* x  = (const float*)d_in[0];
  const float* gw = (const float*)d_in[1];
  const float* gb = (const float*)d_in[2];
  const float* tw = (const float*)d_in[3];
  const float* tb = (const float*)d_in[4];
  const float* pw = (const float*)d_in[5];
  const float* pb = (const float*)d_in[6];
  const float* Ww = (const float*)d_in[7];
  // d_in[8] = W_b: canceled by InstanceNorm -> unused
  float* out = (float*)d_out;
  char* ws = (char*)d_ws;
  // workspace layout (~33 MB)
  unsigned short* thetaT = (unsigned short*)(ws);                        // 2 MB
  unsigned short* phiT   = (unsigned short*)(ws + (2ull << 20));         // 2 MB
  unsigned short* gmat   = (unsigned short*)(ws + (4ull << 20));         // 2 MB
  float* WyT   = (float*)(ws + (8ull << 20));                            // 8 MB
  float* stat  = (float*)(ws + (16ull << 20));                           // 4 KB
  unsigned short* Wwb = (unsigned short*)(ws + (16ull << 20) + 65536);   // 64 KB
  float* lpart = (float*)(ws + (16ull << 20) + (1ull << 19));            // 512 KB
  unsigned short* Opart = (unsigned short*)(ws + (17ull << 20));         // 16 MB

  k_wconv<<<dim3(32), 256, 0, stream>>>(tw, pw, gw, Ww, Wwb, stat);
  k_proj<<<dim3(128, 4), 128, 0, stream>>>(x, gb, tb, pb, Wwb, thetaT, phiT, gmat);
  k_attn<<<dim3(16, 4, KSPLIT), 256, 0, stream>>>(thetaT, phiT, gmat, Opart, lpart);
  k_wy<<<dim3(128, 4), 128, 0, stream>>>(Opart, lpart, Wwb, WyT, stat);
  k_norm<<<dim3(128, 4), 256, 0, stream>>>(WyT, stat, x, out);
}